// Round 13
// baseline (132.185 us; speedup 1.0000x reference)
//
#include <hip/hip_runtime.h>
#include <math.h>

#define B  4
#define N  4096
#define C  128
#define K  16
#define NB 3

typedef unsigned int u32;
typedef unsigned long long u64;
typedef __attribute__((ext_vector_type(8))) short short8_t;
typedef __attribute__((ext_vector_type(4))) float f32x4;

__device__ __forceinline__ float leaky(float x) {
  return x >= 0.f ? x : 0.01f * x;
}
__device__ __forceinline__ unsigned short f2bf(float f) {
  u32 x = __float_as_uint(f);
  return (unsigned short)((x + 0x7FFFu + ((x >> 16) & 1u)) >> 16);  // RNE
}
__device__ __forceinline__ float bflo(u32 u) { return __uint_as_float(u << 16); }
__device__ __forceinline__ float bfhi(u32 u) { return __uint_as_float(u & 0xFFFF0000u); }
__device__ __forceinline__ u32 umaxu(u32 a, u32 b) { return a > b ? a : b; }

// XCD-pair swizzle for the fused pipeline (kept from round 7; harmless).
__device__ __forceinline__ void swz_batch(int bidx, int* b, int* rgrp) {
  int q = bidx >> 3, x = bidx & 7;
  *b = x >> 1;
  *rgrp = (q << 1) | (x & 1);
}

// 64-lane max reduce, pure VALU via DPP. Result valid in lane 63.
__device__ __forceinline__ u32 dpp_max64(u32 v) {
  v = umaxu(v, (u32)__builtin_amdgcn_update_dpp(0, (int)v, 0x111, 0xf, 0xf, false));
  v = umaxu(v, (u32)__builtin_amdgcn_update_dpp(0, (int)v, 0x112, 0xf, 0xf, false));
  v = umaxu(v, (u32)__builtin_amdgcn_update_dpp(0, (int)v, 0x114, 0xf, 0xf, false));
  v = umaxu(v, (u32)__builtin_amdgcn_update_dpp(0, (int)v, 0x118, 0xf, 0xf, false));
  v = umaxu(v, (u32)__builtin_amdgcn_update_dpp(0, (int)v, 0x142, 0xa, 0xf, false));
  v = umaxu(v, (u32)__builtin_amdgcn_update_dpp(0, (int)v, 0x143, 0xc, 0xf, false));
  return v;
}

// exact monotone-encoded squared distance (reference op order, no contraction)
__device__ __forceinline__ u32 encdist(float xi, float yi, float zi, float sqi,
                                       float4 pj) {
  float dt = __fadd_rn(__fmul_rn(xi, pj.x), __fmul_rn(yi, pj.y));
  dt = __fadd_rn(dt, __fmul_rn(zi, pj.z));
  float dd = __fsub_rn(__fadd_rn(sqi, pj.w), __fmul_rn(2.0f, dt));
  u32 bits = __float_as_uint(dd);
  return bits ^ ((u32)(((int)bits) >> 31) | 0x80000000u);
}

// sort survivors descending (64-lane bitonic), emit ranks 1..16
__device__ __forceinline__ void sort_emit(const u64* sv, int total, int lane,
                                          long long outBase, int* idxOut) {
  u64 sk = (lane < total) ? sv[lane] : 0ull;
#pragma unroll
  for (int k2 = 2; k2 <= 64; k2 <<= 1) {
#pragma unroll
    for (int jj = k2 >> 1; jj > 0; jj >>= 1) {
      u64 ok = __shfl_xor(sk, jj, 64);
      bool keepMax = ((lane & jj) == 0) == ((lane & k2) == 0);
      sk = (keepMax == (ok > sk)) ? ok : sk;
    }
  }
  if (lane >= 1 && lane < 17) {
    idxOut[outBase + lane - 1] = 4095 - (int)(u32)sk;
  }
}

// fallback (degenerate ties only; never on this input): exact iterative extract
__device__ __forceinline__ void fallback_row(const float4* p, float4 pi,
                                             u32 lmax, int lt, int lane,
                                             long long outBase, int* idxOut) {
  u32 cmax = lmax; u32 ct = (u32)lt;
  u64 elim = 0ull;
  for (int r = 0; r < 17; ++r) {
    u32 wmax = dpp_max64(cmax);
    u32 s_wmax = (u32)__builtin_amdgcn_readlane((int)wmax, 63);
    u64 mask = __ballot(cmax == s_wmax);
    int s_wj;
    if (__popcll(mask) == 1) {
      int l = (int)(__ffsll((long long)mask) - 1);
      int myj = lane + ((int)ct << 6);
      s_wj = __builtin_amdgcn_readlane(myj, l);
    } else {
      u32 jv = (cmax == s_wmax) ? (u32)(lane + ((int)ct << 6)) : 0xFFFFFFFFu;
#pragma unroll
      for (int off = 1; off < 64; off <<= 1) {
        u32 oj = (u32)__shfl_xor((int)jv, off, 64);
        jv = oj < jv ? oj : jv;
      }
      s_wj = (int)__builtin_amdgcn_readfirstlane((int)jv);
    }
    if (r > 0 && lane == 0) idxOut[outBase + (r - 1)] = s_wj;
    if (r == 16) break;
    if (lane == (s_wj & 63)) {
      elim |= 1ull << (s_wj >> 6);
      cmax = 0u; ct = 0u;
      for (int t = 0; t < 64; ++t) {
        if (elim & (1ull << t)) continue;
        u32 enc = encdist(pi.x, pi.y, pi.z, pi.w, p[lane + (t << 6)]);
        if (enc > cmax) { cmax = enc; ct = (u32)t; }
      }
    }
  }
}

// ---- KNN (faithful: k+1 LARGEST sq-dists, drop first) ----
// 1024 blocks x 512 threads (8 waves). TWO rows per wave, 64 candidates/lane
// per row: each candidate float4 is read ONCE and used for both rows (halves
// the dominant LDS read traffic), and the two rows' dependency chains
// (encdist, bitonic shfl) interleave for 2x ILP at the same wave count.
// VGPR ~110 fits the 128 budget (LDS 72KB -> 2 blocks/CU -> 4 waves/EU; no
// launch_bounds 2nd arg -- round 9 showed it forces a smaller budget + spill).
// Register-lean threshold-select per row (as rounds 10-12):
//  A: hi-16 of enc packed 2/reg + EXACT lane max.  B: bitonic sort of 64
//  exact lane-max keys -> tau = 17th largest.  C: predicate hi16(enc)>=hi16(tau),
//  ballot-compact, survivors recompute exact enc into LDS.  D: bitonic sort
//  survivors; ranks 1..16 out. Key (enc<<32)|(4095-j) == jax top_k order.
__global__ __launch_bounds__(512) void knn_kernel(const float* __restrict__ xyz,
                                                  int* __restrict__ idxOut) {
  __shared__ float4 p[N];          // 64 KB
  __shared__ u64 surv[8][2][64];   // 8 KB survivor buffers (per wave, per row)
  int bidx = blockIdx.x;
  int b = bidx >> 8;               // 256 blocks per batch
  int row0 = (bidx & 255) << 4;    // 16 rows per block
  const float* src = xyz + b * N * 3;
  int tid = threadIdx.x;

  for (int e = tid; e < N; e += 512) {
    float x = src[3 * e], y = src[3 * e + 1], z = src[3 * e + 2];
    // sq = (x*x + y*y) + z*z, exact f32 rounding, no FMA contraction
    float sq = __fadd_rn(__fadd_rn(__fmul_rn(x, x), __fmul_rn(y, y)), __fmul_rn(z, z));
    p[e] = make_float4(x, y, z, sq);
  }
  __syncthreads();

  int lane = tid & 63;
  int wave = tid >> 6;        // 0..7
  int iA = row0 + wave * 2;   // first query row (within batch)
  int iB = iA + 1;            // second query row

  float4 pA = p[iA];
  float4 pB = p[iB];

  // Phase A: distances for BOTH rows per candidate read; pack hi16; exact max
  u32 dA16[32], dB16[32];
  u32 lmA = 0u, lmB = 0u; int ltA = 0, ltB = 0;
#pragma unroll
  for (int t2 = 0; t2 < 32; ++t2) {
    int t0 = t2 * 2, t1 = t0 + 1;
    float4 pj0 = p[lane + (t0 << 6)];
    float4 pj1 = p[lane + (t1 << 6)];
    u32 eA0 = encdist(pA.x, pA.y, pA.z, pA.w, pj0);
    u32 eA1 = encdist(pA.x, pA.y, pA.z, pA.w, pj1);
    u32 eB0 = encdist(pB.x, pB.y, pB.z, pB.w, pj0);
    u32 eB1 = encdist(pB.x, pB.y, pB.z, pB.w, pj1);
    if (eA0 > lmA) { lmA = eA0; ltA = t0; }  // strict > : smallest t on tie
    if (eA1 > lmA) { lmA = eA1; ltA = t1; }
    if (eB0 > lmB) { lmB = eB0; ltB = t0; }
    if (eB1 > lmB) { lmB = eB1; ltB = t1; }
    dA16[t2] = (eA0 >> 16) | (eA1 & 0xFFFF0000u);
    dB16[t2] = (eB0 >> 16) | (eB1 & 0xFFFF0000u);
  }

  // Phase B: dual interleaved bitonic sorts of the exact lane-max keys
  u64 sA = ((u64)lmA << 32) | (u32)(4095 - (lane + (ltA << 6)));
  u64 sB = ((u64)lmB << 32) | (u32)(4095 - (lane + (ltB << 6)));
#pragma unroll
  for (int k2 = 2; k2 <= 64; k2 <<= 1) {
#pragma unroll
    for (int jj = k2 >> 1; jj > 0; jj >>= 1) {
      u64 oA = __shfl_xor(sA, jj, 64);
      u64 oB = __shfl_xor(sB, jj, 64);
      bool keepMax = ((lane & jj) == 0) == ((lane & k2) == 0);
      sA = (keepMax == (oA > sA)) ? oA : sA;
      sB = (keepMax == (oB > sB)) ? oB : sB;
    }
  }
  u32 tA16 = (u32)(__shfl(sA, 16, 64) >> 48);  // hi16 of tauA
  u32 tB16 = (u32)(__shfl(sB, 16, 64) >> 48);  // hi16 of tauB

  // Phase C: ballot-compact survivors for both rows; exact-key store
  int totA = 0, totB = 0;
#pragma unroll
  for (int t = 0; t < 64; ++t) {
    u32 hA = (t & 1) ? (dA16[t >> 1] >> 16) : (dA16[t >> 1] & 0xFFFFu);
    u32 hB = (t & 1) ? (dB16[t >> 1] >> 16) : (dB16[t >> 1] & 0xFFFFu);
    bool pdA = (hA >= tA16);
    bool pdB = (hB >= tB16);
    u64 balA = __ballot(pdA);
    u64 balB = __ballot(pdB);
    if (balA != 0ull) {
      int pos = totA + (int)__builtin_amdgcn_mbcnt_hi(
                           (u32)(balA >> 32),
                           __builtin_amdgcn_mbcnt_lo((u32)balA, 0u));
      if (pdA && pos < 64) {
        u32 enc = encdist(pA.x, pA.y, pA.z, pA.w, p[lane + (t << 6)]);  // exact
        surv[wave][0][pos] = ((u64)enc << 32) | (u32)(4095 - (lane + (t << 6)));
      }
      totA += (int)__popcll(balA);
    }
    if (balB != 0ull) {
      int pos = totB + (int)__builtin_amdgcn_mbcnt_hi(
                           (u32)(balB >> 32),
                           __builtin_amdgcn_mbcnt_lo((u32)balB, 0u));
      if (pdB && pos < 64) {
        u32 enc = encdist(pB.x, pB.y, pB.z, pB.w, p[lane + (t << 6)]);  // exact
        surv[wave][1][pos] = ((u64)enc << 32) | (u32)(4095 - (lane + (t << 6)));
      }
      totB += (int)__popcll(balB);
    }
  }

  long long outA = ((long long)(b * N + iA)) * K;
  long long outB = ((long long)(b * N + iB)) * K;

  if (totA <= 64 && totB <= 64) {
    // Phase D: dual interleaved bitonic sorts; emit ranks 1..16 for both rows
    u64 kA = (lane < totA) ? surv[wave][0][lane] : 0ull;
    u64 kB = (lane < totB) ? surv[wave][1][lane] : 0ull;
#pragma unroll
    for (int k2 = 2; k2 <= 64; k2 <<= 1) {
#pragma unroll
      for (int jj = k2 >> 1; jj > 0; jj >>= 1) {
        u64 oA = __shfl_xor(kA, jj, 64);
        u64 oB = __shfl_xor(kB, jj, 64);
        bool keepMax = ((lane & jj) == 0) == ((lane & k2) == 0);
        kA = (keepMax == (oA > kA)) ? oA : kA;
        kB = (keepMax == (oB > kB)) ? oB : kB;
      }
    }
    if (lane >= 1 && lane < 17) {
      idxOut[outA + lane - 1] = 4095 - (int)(u32)kA;
      idxOut[outB + lane - 1] = 4095 - (int)(u32)kB;
    }
  } else {
    if (totA <= 64) sort_emit(surv[wave][0], totA, lane, outA, idxOut);
    else            fallback_row(p, pA, lmA, ltA, lane, outA, idxOut);
    if (totB <= 64) sort_emit(surv[wave][1], totB, lane, outB, idxOut);
    else            fallback_row(p, pB, lmB, ltB, lane, outB, idxOut);
  }
}

// ---- Abf = bf16(leaky(P)) : XCD-pair swizzled ----
__global__ __launch_bounds__(256) void cvtA_kernel(const float* __restrict__ P,
                                                   unsigned short* __restrict__ Abf) {
  int b, rgrp;
  swz_batch(blockIdx.x, &b, &rgrp);
  int tid = threadIdx.x;
  size_t off = ((size_t)b * N + rgrp * 16 + (tid >> 4)) * C + (tid & 15) * 8;
  const float4* p4 = (const float4*)(P + off);
  float4 a = p4[0], c = p4[1];
  unsigned short u0 = f2bf(leaky(a.x)), u1 = f2bf(leaky(a.y));
  unsigned short u2 = f2bf(leaky(a.z)), u3 = f2bf(leaky(a.w));
  unsigned short u4 = f2bf(leaky(c.x)), u5 = f2bf(leaky(c.y));
  unsigned short u6 = f2bf(leaky(c.z)), u7 = f2bf(leaky(c.w));
  uint4 o;
  o.x = (u32)u0 | ((u32)u1 << 16);
  o.y = (u32)u2 | ((u32)u3 << 16);
  o.z = (u32)u4 | ((u32)u5 << 16);
  o.w = (u32)u6 | ((u32)u7 << 16);
  *(uint4*)(Abf + off) = o;
}

// ---- W (f32) -> bf16, all 3 blocks at once ----
__global__ __launch_bounds__(256) void cvtW_kernel(const float* __restrict__ Wc,
                                                   const float* __restrict__ Wg,
                                                   unsigned short* __restrict__ Wbf) {
  int e = blockIdx.x * 256 + threadIdx.x;  // 0..98303
  if (e < NB * C * C) Wbf[e] = f2bf(Wc[e]);
  else Wbf[e] = f2bf(Wg[e - NB * C * C]);
}

// ---- fused per-block-iter: gather-sum (bf16) + dual MFMA matmul + epilogue
__global__ __launch_bounds__(256) void fused_kernel(
    const float* __restrict__ Pcur, const unsigned short* __restrict__ Abf,
    const int* __restrict__ idx,
    const unsigned short* __restrict__ Wcbf, const unsigned short* __restrict__ Wgbf,
    const float* __restrict__ bc, const float* __restrict__ bg,
    float* __restrict__ Pnxt, unsigned short* __restrict__ AbfN) {
  __shared__ int ji[256];
  __shared__ unsigned short Sl[16][136];  // +8 pad: 272B row stride, 16B aligned
  int bb, rgrp;
  swz_batch(blockIdx.x, &bb, &rgrp);
  int row0 = bb * N + rgrp * 16;  // global row
  int tid = threadIdx.x;
  ji[tid] = idx[row0 * K + tid];
  __syncthreads();

  // batch base for neighbor indices (idx entries are within-batch!)
  const unsigned short* AbfB = Abf + ((size_t)bb << 12) * C;

  // gather: thread (r,g) sums 8 cols [g*8, g*8+8) of row r over 16 neighbors
  {
    int r = tid >> 4, g = tid & 15;
    float s0 = 0.f, s1 = 0.f, s2 = 0.f, s3 = 0.f, s4 = 0.f, s5 = 0.f, s6 = 0.f, s7 = 0.f;
#pragma unroll
    for (int t = 0; t < K; ++t) {
      int j = ji[(r << 4) + t];
      uint4 v = *(const uint4*)(AbfB + (size_t)j * C + g * 8);
      s0 += bflo(v.x); s1 += bfhi(v.x);
      s2 += bflo(v.y); s3 += bfhi(v.y);
      s4 += bflo(v.z); s5 += bfhi(v.z);
      s6 += bflo(v.w); s7 += bfhi(v.w);
    }
    uint4 o;
    o.x = (u32)f2bf(s0) | ((u32)f2bf(s1) << 16);
    o.y = (u32)f2bf(s2) | ((u32)f2bf(s3) << 16);
    o.z = (u32)f2bf(s4) | ((u32)f2bf(s5) << 16);
    o.w = (u32)f2bf(s6) | ((u32)f2bf(s7) << 16);
    *(uint4*)(&Sl[r][g * 8]) = o;
  }
  __syncthreads();

  // MFMA: A row = lane&15, k-chunk = (lane>>4)*8 ; B col = lane&15, same k-chunk
  int lane = tid & 63, wave = tid >> 6;
  int lrow = lane & 15;
  int kgrp = (lane >> 4) * 8;
  f32x4 acc0 = {0.f, 0.f, 0.f, 0.f};
  f32x4 acc1 = {0.f, 0.f, 0.f, 0.f};
  int ct0 = wave * 2, ct1 = ct0 + 1;
  const unsigned short* abase = Abf + (size_t)(row0 + lrow) * C + kgrp;
  const unsigned short* wc0 = Wcbf + (size_t)(ct0 * 16 + lrow) * C + kgrp;
  const unsigned short* wc1 = Wcbf + (size_t)(ct1 * 16 + lrow) * C + kgrp;
  const unsigned short* wg0 = Wgbf + (size_t)(ct0 * 16 + lrow) * C + kgrp;
  const unsigned short* wg1 = Wgbf + (size_t)(ct1 * 16 + lrow) * C + kgrp;
#pragma unroll
  for (int ks = 0; ks < 4; ++ks) {
    short8_t a = *(const short8_t*)(abase + ks * 32);
    short8_t b0 = *(const short8_t*)(wc0 + ks * 32);
    short8_t b1 = *(const short8_t*)(wc1 + ks * 32);
    acc0 = __builtin_amdgcn_mfma_f32_16x16x32_bf16(a, b0, acc0, 0, 0, 0);
    acc1 = __builtin_amdgcn_mfma_f32_16x16x32_bf16(a, b1, acc1, 0, 0, 0);
  }
#pragma unroll
  for (int ks = 0; ks < 4; ++ks) {
    short8_t sf = *(const short8_t*)(&Sl[lrow][kgrp + ks * 32]);
    short8_t b0 = *(const short8_t*)(wg0 + ks * 32);
    short8_t b1 = *(const short8_t*)(wg1 + ks * 32);
    acc0 = __builtin_amdgcn_mfma_f32_16x16x32_bf16(sf, b0, acc0, 0, 0, 0);
    acc1 = __builtin_amdgcn_mfma_f32_16x16x32_bf16(sf, b1, acc1, 0, 0, 0);
  }

  // epilogue: D row=(lane>>4)*4+q, col=lane&15 (within 16x16 tile)
#pragma unroll
  for (int side = 0; side < 2; ++side) {
    int col = (side == 0 ? ct0 : ct1) * 16 + lrow;
    float bias = bc[col] + 16.0f * bg[col];
    f32x4 acc = (side == 0) ? acc0 : acc1;
#pragma unroll
    for (int q = 0; q < 4; ++q) {
      int row = row0 + (lane >> 4) * 4 + q;
      float v = (acc[q] + bias) * (1.0f / 17.0f);
      float vn = v + Pcur[(size_t)row * C + col];
      Pnxt[(size_t)row * C + col] = vn;
      if (AbfN) AbfN[(size_t)row * C + col] = f2bf(leaky(vn));
    }
  }
}

extern "C" void kernel_launch(void* const* d_in, const int* in_sizes, int n_in,
                              void* d_out, int out_size, void* d_ws, size_t ws_size,
                              hipStream_t stream) {
  const float* xyz = (const float*)d_in[0];
  const float* pts = (const float*)d_in[1];
  const float* Wc = (const float*)d_in[5];
  const float* bc = (const float*)d_in[6];
  const float* Wg = (const float*)d_in[7];
  const float* bg = (const float*)d_in[8];

  const size_t PE = (size_t)B * N * C;            // 2097152 elements
  const size_t idxB = (size_t)B * N * K * 4;      // 1 MB
  const size_t WbfB = (size_t)2 * NB * C * C * 2; // 192 KB
  char* ws = (char*)d_ws;
  float* Pa            = (float*)ws;                                  // 8 MB
  int* idx             = (int*)(ws + PE * 4);                         // 1 MB
  unsigned short* Abf0 = (unsigned short*)(ws + PE * 4 + idxB);       // 4 MB
  unsigned short* Wbf  = (unsigned short*)(ws + PE * 4 + idxB + PE * 2);
  unsigned short* Abf1 = (unsigned short*)(ws + PE * 4 + idxB + PE * 2 + WbfB);
  unsigned short* Wcbf = Wbf;
  unsigned short* Wgbf = Wbf + (size_t)NB * C * C;
  const size_t need = PE * 4 + idxB + PE * 2 + WbfB + PE * 2;  // 17.2 MB
  const bool fusedAbf = (ws_size >= need);

  hipLaunchKernelGGL(cvtW_kernel, dim3((2 * NB * C * C) / 256), dim3(256), 0, stream,
                     Wc, Wg, Wbf);
  hipLaunchKernelGGL(cvtA_kernel, dim3(1024), dim3(256), 0, stream, pts, Abf0);
  hipLaunchKernelGGL(knn_kernel, dim3(1024), dim3(512), 0, stream, xyz, idx);

  // ping-pong: pts (read-only) -> d_out -> Pa -> d_out
  const float* cur = pts;
  float* nxt = (float*)d_out;
  unsigned short* AbfCur = Abf0;
  unsigned short* AbfNxt = fusedAbf ? Abf1 : Abf0;
  for (int i = 0; i < NB; ++i) {
    if (!fusedAbf && i > 0) {
      hipLaunchKernelGGL(cvtA_kernel, dim3(1024), dim3(256), 0, stream, cur, Abf0);
      AbfCur = Abf0;
    }
    unsigned short* an = (fusedAbf && i < NB - 1) ? AbfNxt : (unsigned short*)nullptr;
    hipLaunchKernelGGL(fused_kernel, dim3(1024), dim3(256), 0, stream,
                       cur, AbfCur, idx, Wcbf + (size_t)i * C * C, Wgbf + (size_t)i * C * C,
                       bc + (size_t)i * C, bg + (size_t)i * C, nxt, an);
    cur = nxt;
    nxt = (i == 0) ? Pa : (float*)d_out;
    if (fusedAbf) { unsigned short* ta = AbfCur; AbfCur = AbfNxt; AbfNxt = ta; }
  }
}

// Round 14
// 117.170 us; speedup vs baseline: 1.1281x; 1.1281x over previous
//
#include <hip/hip_runtime.h>
#include <math.h>

#define B  4
#define N  4096
#define C  128
#define K  16
#define NB 3

typedef unsigned int u32;
typedef unsigned long long u64;
typedef __attribute__((ext_vector_type(8))) short short8_t;
typedef __attribute__((ext_vector_type(4))) float f32x4;

__device__ __forceinline__ float leaky(float x) {
  return x >= 0.f ? x : 0.01f * x;
}
__device__ __forceinline__ unsigned short f2bf(float f) {
  u32 x = __float_as_uint(f);
  return (unsigned short)((x + 0x7FFFu + ((x >> 16) & 1u)) >> 16);  // RNE
}
__device__ __forceinline__ float bflo(u32 u) { return __uint_as_float(u << 16); }
__device__ __forceinline__ float bfhi(u32 u) { return __uint_as_float(u & 0xFFFF0000u); }
__device__ __forceinline__ u32 umaxu(u32 a, u32 b) { return a > b ? a : b; }

// XCD-pair swizzle for the fused pipeline (kept from round 7; harmless).
__device__ __forceinline__ void swz_batch(int bidx, int* b, int* rgrp) {
  int q = bidx >> 3, x = bidx & 7;
  *b = x >> 1;
  *rgrp = (q << 1) | (x & 1);
}

// 64-lane max reduce, pure VALU via DPP. Result valid in lane 63.
__device__ __forceinline__ u32 dpp_max64(u32 v) {
  v = umaxu(v, (u32)__builtin_amdgcn_update_dpp(0, (int)v, 0x111, 0xf, 0xf, false));
  v = umaxu(v, (u32)__builtin_amdgcn_update_dpp(0, (int)v, 0x112, 0xf, 0xf, false));
  v = umaxu(v, (u32)__builtin_amdgcn_update_dpp(0, (int)v, 0x114, 0xf, 0xf, false));
  v = umaxu(v, (u32)__builtin_amdgcn_update_dpp(0, (int)v, 0x118, 0xf, 0xf, false));
  v = umaxu(v, (u32)__builtin_amdgcn_update_dpp(0, (int)v, 0x142, 0xa, 0xf, false));
  v = umaxu(v, (u32)__builtin_amdgcn_update_dpp(0, (int)v, 0x143, 0xc, 0xf, false));
  return v;
}

// inclusive prefix-sum across 64 lanes, pure VALU via DPP (row_shr + bcast)
__device__ __forceinline__ u32 dpp_scan64(u32 v) {
  v += (u32)__builtin_amdgcn_update_dpp(0, (int)v, 0x111, 0xf, 0xf, false);
  v += (u32)__builtin_amdgcn_update_dpp(0, (int)v, 0x112, 0xf, 0xf, false);
  v += (u32)__builtin_amdgcn_update_dpp(0, (int)v, 0x114, 0xf, 0xf, false);
  v += (u32)__builtin_amdgcn_update_dpp(0, (int)v, 0x118, 0xf, 0xf, false);
  v += (u32)__builtin_amdgcn_update_dpp(0, (int)v, 0x142, 0xa, 0xf, false);
  v += (u32)__builtin_amdgcn_update_dpp(0, (int)v, 0x143, 0xc, 0xf, false);
  return v;
}

// exact monotone-encoded squared distance (reference op order, no contraction)
__device__ __forceinline__ u32 encdist(float xi, float yi, float zi, float sqi,
                                       float4 pj) {
  float dt = __fadd_rn(__fmul_rn(xi, pj.x), __fmul_rn(yi, pj.y));
  dt = __fadd_rn(dt, __fmul_rn(zi, pj.z));
  float dd = __fsub_rn(__fadd_rn(sqi, pj.w), __fmul_rn(2.0f, dt));
  u32 bits = __float_as_uint(dd);
  return bits ^ ((u32)(((int)bits) >> 31) | 0x80000000u);
}

// sort survivors descending (64-lane bitonic), emit ranks 1..16
__device__ __forceinline__ void sort_emit(const u64* sv, int total, int lane,
                                          long long outBase, int* idxOut) {
  u64 sk = (lane < total) ? sv[lane] : 0ull;
#pragma unroll
  for (int k2 = 2; k2 <= 64; k2 <<= 1) {
#pragma unroll
    for (int jj = k2 >> 1; jj > 0; jj >>= 1) {
      u64 ok = __shfl_xor(sk, jj, 64);
      bool keepMax = ((lane & jj) == 0) == ((lane & k2) == 0);
      sk = (keepMax == (ok > sk)) ? ok : sk;
    }
  }
  if (lane >= 1 && lane < 17) {
    idxOut[outBase + lane - 1] = 4095 - (int)(u32)sk;
  }
}

// fallback (degenerate ties only; never on this input): exact iterative extract
__device__ __forceinline__ void fallback_row(const float4* p, float4 pi,
                                             u32 lmax, int lt, int lane,
                                             long long outBase, int* idxOut) {
  u32 cmax = lmax; u32 ct = (u32)lt;
  u64 elim = 0ull;
  for (int r = 0; r < 17; ++r) {
    u32 wmax = dpp_max64(cmax);
    u32 s_wmax = (u32)__builtin_amdgcn_readlane((int)wmax, 63);
    u64 mask = __ballot(cmax == s_wmax);
    int s_wj;
    if (__popcll(mask) == 1) {
      int l = (int)(__ffsll((long long)mask) - 1);
      int myj = lane + ((int)ct << 6);
      s_wj = __builtin_amdgcn_readlane(myj, l);
    } else {
      u32 jv = (cmax == s_wmax) ? (u32)(lane + ((int)ct << 6)) : 0xFFFFFFFFu;
#pragma unroll
      for (int off = 1; off < 64; off <<= 1) {
        u32 oj = (u32)__shfl_xor((int)jv, off, 64);
        jv = oj < jv ? oj : jv;
      }
      s_wj = (int)__builtin_amdgcn_readfirstlane((int)jv);
    }
    if (r > 0 && lane == 0) idxOut[outBase + (r - 1)] = s_wj;
    if (r == 16) break;
    if (lane == (s_wj & 63)) {
      elim |= 1ull << (s_wj >> 6);
      cmax = 0u; ct = 0u;
      for (int t = 0; t < 64; ++t) {
        if (elim & (1ull << t)) continue;
        u32 enc = encdist(pi.x, pi.y, pi.z, pi.w, p[lane + (t << 6)]);
        if (enc > cmax) { cmax = enc; ct = (u32)t; }
      }
    }
  }
}

// ---- KNN (faithful: k+1 LARGEST sq-dists, drop first) ----
// 2048 blocks x 512 threads (8 waves). ONE wave per row, 64 candidates/lane
// (round-11 structure: 53.9us, VGPR 52, no spill; rounds 12/13 alternatives
// regressed). Register-lean threshold-select:
//  A: hi-16 of enc packed 2/reg (denc16[32]) + EXACT per-lane max.
//  B: bitonic sort of the 64 lane-max VALUES only (u32: tau needs no index;
//     ties safe since predicate is >=) -> tau16 = hi16 of 17th largest.
//  C: per-lane survivor bitmask (NO per-slot ballots -- round 11 serialized
//     64 ballot->scalar round-trips here), 6-step DPP prefix-sum of counts,
//     each lane writes its own ~0-3 survivors with exact recomputed enc.
//     Survivor order is lane-major (different from r11) -- irrelevant: keys
//     are distinct and Phase D fully sorts.
//  D: bitonic sort survivors; ranks 1..16 out (rank 0 = dropped max).
// Key (enc<<32)|(4095-j) == jax top_k order (value desc, index asc).
// Fallback if total > 64 (degenerate ties only): exact iterative extract.
__global__ __launch_bounds__(512) void knn_kernel(const float* __restrict__ xyz,
                                                  int* __restrict__ idxOut) {
  __shared__ float4 p[N];       // 64 KB
  __shared__ u64 surv[8][64];   // 4 KB survivor buffer, per wave
  int bidx = blockIdx.x;
  int b = bidx >> 9;            // 512 blocks per batch
  int row0 = (bidx & 511) << 3; // 8 rows per block
  const float* src = xyz + b * N * 3;
  int tid = threadIdx.x;

  for (int e = tid; e < N; e += 512) {
    float x = src[3 * e], y = src[3 * e + 1], z = src[3 * e + 2];
    // sq = (x*x + y*y) + z*z, exact f32 rounding, no FMA contraction
    float sq = __fadd_rn(__fadd_rn(__fmul_rn(x, x), __fmul_rn(y, y)), __fmul_rn(z, z));
    p[e] = make_float4(x, y, z, sq);
  }
  __syncthreads();

  int lane = tid & 63;
  int wave = tid >> 6;   // 0..7 = local row
  int i = row0 + wave;   // query point within batch

  float4 pi = p[i];
  float xi = pi.x, yi = pi.y, zi = pi.z, sqi = pi.w;

  // Phase A: distances; pack hi16; exact per-lane argmax
  u32 denc16[32];
  u32 lmax = 0u; int lt = 0;
#pragma unroll
  for (int t2 = 0; t2 < 32; ++t2) {
    int t0 = t2 * 2, t1 = t0 + 1;
    float4 pj0 = p[lane + (t0 << 6)];
    float4 pj1 = p[lane + (t1 << 6)];
    u32 e0 = encdist(xi, yi, zi, sqi, pj0);
    u32 e1 = encdist(xi, yi, zi, sqi, pj1);
    if (e0 > lmax) { lmax = e0; lt = t0; }  // strict > : smallest t on tie
    if (e1 > lmax) { lmax = e1; lt = t1; }
    denc16[t2] = (e0 >> 16) | (e1 & 0xFFFF0000u);
  }

  // Phase B: bitonic sort of the 64 lane-max VALUES (desc); tau = 17th largest
  u32 sv = lmax;
#pragma unroll
  for (int k2 = 2; k2 <= 64; k2 <<= 1) {
#pragma unroll
    for (int jj = k2 >> 1; jj > 0; jj >>= 1) {
      u32 ov = (u32)__shfl_xor((int)sv, jj, 64);
      bool keepMax = ((lane & jj) == 0) == ((lane & k2) == 0);
      sv = (keepMax == (ov > sv)) ? ov : sv;
    }
  }
  u32 tau16 = ((u32)__shfl((int)sv, 16, 64)) >> 16;  // hi16 of tau value

  // Phase C: per-lane survivor mask + DPP prefix-sum + own-survivor writes
  u32 maskLo = 0u, maskHi = 0u;
#pragma unroll
  for (int t2 = 0; t2 < 16; ++t2) {
    u32 pr = denc16[t2];
    maskLo |= ((pr & 0xFFFFu) >= tau16 ? 1u : 0u) << (2 * t2);
    maskLo |= ((pr >> 16) >= tau16 ? 1u : 0u) << (2 * t2 + 1);
  }
#pragma unroll
  for (int t2 = 16; t2 < 32; ++t2) {
    u32 pr = denc16[t2];
    maskHi |= ((pr & 0xFFFFu) >= tau16 ? 1u : 0u) << (2 * (t2 - 16));
    maskHi |= ((pr >> 16) >= tau16 ? 1u : 0u) << (2 * (t2 - 16) + 1);
  }
  u32 cnt = (u32)(__popc(maskLo) + __popc(maskHi));
  u32 incl = dpp_scan64(cnt);
  int total = __builtin_amdgcn_readlane((int)incl, 63);
  int pos = (int)(incl - cnt);  // exclusive base for this lane
  u32 m = maskLo;
  while (m) {
    int t = __builtin_ctz(m);
    m &= m - 1u;
    if (pos < 64) {
      u32 enc = encdist(xi, yi, zi, sqi, p[lane + (t << 6)]);  // exact
      surv[wave][pos] = ((u64)enc << 32) | (u32)(4095 - (lane + (t << 6)));
    }
    ++pos;
  }
  m = maskHi;
  while (m) {
    int t = 32 + __builtin_ctz(m);
    m &= m - 1u;
    if (pos < 64) {
      u32 enc = encdist(xi, yi, zi, sqi, p[lane + (t << 6)]);  // exact
      surv[wave][pos] = ((u64)enc << 32) | (u32)(4095 - (lane + (t << 6)));
    }
    ++pos;
  }

  long long outBase = ((long long)(b * N + i)) * K;
  if (total <= 64) {
    sort_emit(surv[wave], total, lane, outBase, idxOut);
  } else {
    fallback_row(p, pi, lmax, lt, lane, outBase, idxOut);
  }
}

// ---- Abf = bf16(leaky(P)) : XCD-pair swizzled ----
__global__ __launch_bounds__(256) void cvtA_kernel(const float* __restrict__ P,
                                                   unsigned short* __restrict__ Abf) {
  int b, rgrp;
  swz_batch(blockIdx.x, &b, &rgrp);
  int tid = threadIdx.x;
  size_t off = ((size_t)b * N + rgrp * 16 + (tid >> 4)) * C + (tid & 15) * 8;
  const float4* p4 = (const float4*)(P + off);
  float4 a = p4[0], c = p4[1];
  unsigned short u0 = f2bf(leaky(a.x)), u1 = f2bf(leaky(a.y));
  unsigned short u2 = f2bf(leaky(a.z)), u3 = f2bf(leaky(a.w));
  unsigned short u4 = f2bf(leaky(c.x)), u5 = f2bf(leaky(c.y));
  unsigned short u6 = f2bf(leaky(c.z)), u7 = f2bf(leaky(c.w));
  uint4 o;
  o.x = (u32)u0 | ((u32)u1 << 16);
  o.y = (u32)u2 | ((u32)u3 << 16);
  o.z = (u32)u4 | ((u32)u5 << 16);
  o.w = (u32)u6 | ((u32)u7 << 16);
  *(uint4*)(Abf + off) = o;
}

// ---- W (f32) -> bf16, all 3 blocks at once ----
__global__ __launch_bounds__(256) void cvtW_kernel(const float* __restrict__ Wc,
                                                   const float* __restrict__ Wg,
                                                   unsigned short* __restrict__ Wbf) {
  int e = blockIdx.x * 256 + threadIdx.x;  // 0..98303
  if (e < NB * C * C) Wbf[e] = f2bf(Wc[e]);
  else Wbf[e] = f2bf(Wg[e - NB * C * C]);
}

// ---- fused per-block-iter: gather-sum (bf16) + dual MFMA matmul + epilogue
__global__ __launch_bounds__(256) void fused_kernel(
    const float* __restrict__ Pcur, const unsigned short* __restrict__ Abf,
    const int* __restrict__ idx,
    const unsigned short* __restrict__ Wcbf, const unsigned short* __restrict__ Wgbf,
    const float* __restrict__ bc, const float* __restrict__ bg,
    float* __restrict__ Pnxt, unsigned short* __restrict__ AbfN) {
  __shared__ int ji[256];
  __shared__ unsigned short Sl[16][136];  // +8 pad: 272B row stride, 16B aligned
  int bb, rgrp;
  swz_batch(blockIdx.x, &bb, &rgrp);
  int row0 = bb * N + rgrp * 16;  // global row
  int tid = threadIdx.x;
  ji[tid] = idx[row0 * K + tid];
  __syncthreads();

  // batch base for neighbor indices (idx entries are within-batch!)
  const unsigned short* AbfB = Abf + ((size_t)bb << 12) * C;

  // gather: thread (r,g) sums 8 cols [g*8, g*8+8) of row r over 16 neighbors
  {
    int r = tid >> 4, g = tid & 15;
    float s0 = 0.f, s1 = 0.f, s2 = 0.f, s3 = 0.f, s4 = 0.f, s5 = 0.f, s6 = 0.f, s7 = 0.f;
#pragma unroll
    for (int t = 0; t < K; ++t) {
      int j = ji[(r << 4) + t];
      uint4 v = *(const uint4*)(AbfB + (size_t)j * C + g * 8);
      s0 += bflo(v.x); s1 += bfhi(v.x);
      s2 += bflo(v.y); s3 += bfhi(v.y);
      s4 += bflo(v.z); s5 += bfhi(v.z);
      s6 += bflo(v.w); s7 += bfhi(v.w);
    }
    uint4 o;
    o.x = (u32)f2bf(s0) | ((u32)f2bf(s1) << 16);
    o.y = (u32)f2bf(s2) | ((u32)f2bf(s3) << 16);
    o.z = (u32)f2bf(s4) | ((u32)f2bf(s5) << 16);
    o.w = (u32)f2bf(s6) | ((u32)f2bf(s7) << 16);
    *(uint4*)(&Sl[r][g * 8]) = o;
  }
  __syncthreads();

  // MFMA: A row = lane&15, k-chunk = (lane>>4)*8 ; B col = lane&15, same k-chunk
  int lane = tid & 63, wave = tid >> 6;
  int lrow = lane & 15;
  int kgrp = (lane >> 4) * 8;
  f32x4 acc0 = {0.f, 0.f, 0.f, 0.f};
  f32x4 acc1 = {0.f, 0.f, 0.f, 0.f};
  int ct0 = wave * 2, ct1 = ct0 + 1;
  const unsigned short* abase = Abf + (size_t)(row0 + lrow) * C + kgrp;
  const unsigned short* wc0 = Wcbf + (size_t)(ct0 * 16 + lrow) * C + kgrp;
  const unsigned short* wc1 = Wcbf + (size_t)(ct1 * 16 + lrow) * C + kgrp;
  const unsigned short* wg0 = Wgbf + (size_t)(ct0 * 16 + lrow) * C + kgrp;
  const unsigned short* wg1 = Wgbf + (size_t)(ct1 * 16 + lrow) * C + kgrp;
#pragma unroll
  for (int ks = 0; ks < 4; ++ks) {
    short8_t a = *(const short8_t*)(abase + ks * 32);
    short8_t b0 = *(const short8_t*)(wc0 + ks * 32);
    short8_t b1 = *(const short8_t*)(wc1 + ks * 32);
    acc0 = __builtin_amdgcn_mfma_f32_16x16x32_bf16(a, b0, acc0, 0, 0, 0);
    acc1 = __builtin_amdgcn_mfma_f32_16x16x32_bf16(a, b1, acc1, 0, 0, 0);
  }
#pragma unroll
  for (int ks = 0; ks < 4; ++ks) {
    short8_t sf = *(const short8_t*)(&Sl[lrow][kgrp + ks * 32]);
    short8_t b0 = *(const short8_t*)(wg0 + ks * 32);
    short8_t b1 = *(const short8_t*)(wg1 + ks * 32);
    acc0 = __builtin_amdgcn_mfma_f32_16x16x32_bf16(sf, b0, acc0, 0, 0, 0);
    acc1 = __builtin_amdgcn_mfma_f32_16x16x32_bf16(sf, b1, acc1, 0, 0, 0);
  }

  // epilogue: D row=(lane>>4)*4+q, col=lane&15 (within 16x16 tile)
#pragma unroll
  for (int side = 0; side < 2; ++side) {
    int col = (side == 0 ? ct0 : ct1) * 16 + lrow;
    float bias = bc[col] + 16.0f * bg[col];
    f32x4 acc = (side == 0) ? acc0 : acc1;
#pragma unroll
    for (int q = 0; q < 4; ++q) {
      int row = row0 + (lane >> 4) * 4 + q;
      float v = (acc[q] + bias) * (1.0f / 17.0f);
      float vn = v + Pcur[(size_t)row * C + col];
      Pnxt[(size_t)row * C + col] = vn;
      if (AbfN) AbfN[(size_t)row * C + col] = f2bf(leaky(vn));
    }
  }
}

extern "C" void kernel_launch(void* const* d_in, const int* in_sizes, int n_in,
                              void* d_out, int out_size, void* d_ws, size_t ws_size,
                              hipStream_t stream) {
  const float* xyz = (const float*)d_in[0];
  const float* pts = (const float*)d_in[1];
  const float* Wc = (const float*)d_in[5];
  const float* bc = (const float*)d_in[6];
  const float* Wg = (const float*)d_in[7];
  const float* bg = (const float*)d_in[8];

  const size_t PE = (size_t)B * N * C;            // 2097152 elements
  const size_t idxB = (size_t)B * N * K * 4;      // 1 MB
  const size_t WbfB = (size_t)2 * NB * C * C * 2; // 192 KB
  char* ws = (char*)d_ws;
  float* Pa            = (float*)ws;                                  // 8 MB
  int* idx             = (int*)(ws + PE * 4);                         // 1 MB
  unsigned short* Abf0 = (unsigned short*)(ws + PE * 4 + idxB);       // 4 MB
  unsigned short* Wbf  = (unsigned short*)(ws + PE * 4 + idxB + PE * 2);
  unsigned short* Abf1 = (unsigned short*)(ws + PE * 4 + idxB + PE * 2 + WbfB);
  unsigned short* Wcbf = Wbf;
  unsigned short* Wgbf = Wbf + (size_t)NB * C * C;
  const size_t need = PE * 4 + idxB + PE * 2 + WbfB + PE * 2;  // 17.2 MB
  const bool fusedAbf = (ws_size >= need);

  hipLaunchKernelGGL(cvtW_kernel, dim3((2 * NB * C * C) / 256), dim3(256), 0, stream,
                     Wc, Wg, Wbf);
  hipLaunchKernelGGL(cvtA_kernel, dim3(1024), dim3(256), 0, stream, pts, Abf0);
  hipLaunchKernelGGL(knn_kernel, dim3(2048), dim3(512), 0, stream, xyz, idx);

  // ping-pong: pts (read-only) -> d_out -> Pa -> d_out
  const float* cur = pts;
  float* nxt = (float*)d_out;
  unsigned short* AbfCur = Abf0;
  unsigned short* AbfNxt = fusedAbf ? Abf1 : Abf0;
  for (int i = 0; i < NB; ++i) {
    if (!fusedAbf && i > 0) {
      hipLaunchKernelGGL(cvtA_kernel, dim3(1024), dim3(256), 0, stream, cur, Abf0);
      AbfCur = Abf0;
    }
    unsigned short* an = (fusedAbf && i < NB - 1) ? AbfNxt : (unsigned short*)nullptr;
    hipLaunchKernelGGL(fused_kernel, dim3(1024), dim3(256), 0, stream,
                       cur, AbfCur, idx, Wcbf + (size_t)i * C * C, Wgbf + (size_t)i * C * C,
                       bc + (size_t)i * C, bg + (size_t)i * C, nxt, an);
    cur = nxt;
    nxt = (i == 0) ? Pa : (float*)d_out;
    if (fusedAbf) { unsigned short* ta = AbfCur; AbfCur = AbfNxt; AbfNxt = ta; }
  }
}

// Round 15
// 105.413 us; speedup vs baseline: 1.2540x; 1.1115x over previous
//
#include <hip/hip_runtime.h>
#include <math.h>

#define B  4
#define N  4096
#define C  128
#define K  16
#define NB 3
#define RB 32  // fused: rows per block

typedef unsigned int u32;
typedef unsigned long long u64;
typedef __attribute__((ext_vector_type(8))) short short8_t;
typedef __attribute__((ext_vector_type(4))) float f32x4;

__device__ __forceinline__ float leaky(float x) {
  return x >= 0.f ? x : 0.01f * x;
}
__device__ __forceinline__ unsigned short f2bf(float f) {
  u32 x = __float_as_uint(f);
  return (unsigned short)((x + 0x7FFFu + ((x >> 16) & 1u)) >> 16);  // RNE
}
__device__ __forceinline__ float bflo(u32 u) { return __uint_as_float(u << 16); }
__device__ __forceinline__ float bfhi(u32 u) { return __uint_as_float(u & 0xFFFF0000u); }
__device__ __forceinline__ u32 umaxu(u32 a, u32 b) { return a > b ? a : b; }

// XCD-pair swizzle: bidx=(q*8+x) -> batch b=x>>1, row-group rgrp=2q+(x&1).
__device__ __forceinline__ void swz_batch(int bidx, int* b, int* rgrp) {
  int q = bidx >> 3, x = bidx & 7;
  *b = x >> 1;
  *rgrp = (q << 1) | (x & 1);
}

// 64-lane max reduce, pure VALU via DPP. Result valid in lane 63.
__device__ __forceinline__ u32 dpp_max64(u32 v) {
  v = umaxu(v, (u32)__builtin_amdgcn_update_dpp(0, (int)v, 0x111, 0xf, 0xf, false));
  v = umaxu(v, (u32)__builtin_amdgcn_update_dpp(0, (int)v, 0x112, 0xf, 0xf, false));
  v = umaxu(v, (u32)__builtin_amdgcn_update_dpp(0, (int)v, 0x114, 0xf, 0xf, false));
  v = umaxu(v, (u32)__builtin_amdgcn_update_dpp(0, (int)v, 0x118, 0xf, 0xf, false));
  v = umaxu(v, (u32)__builtin_amdgcn_update_dpp(0, (int)v, 0x142, 0xa, 0xf, false));
  v = umaxu(v, (u32)__builtin_amdgcn_update_dpp(0, (int)v, 0x143, 0xc, 0xf, false));
  return v;
}

// exact monotone-encoded squared distance (reference op order, no contraction)
__device__ __forceinline__ u32 encdist(float xi, float yi, float zi, float sqi,
                                       float4 pj) {
  float dt = __fadd_rn(__fmul_rn(xi, pj.x), __fmul_rn(yi, pj.y));
  dt = __fadd_rn(dt, __fmul_rn(zi, pj.z));
  float dd = __fsub_rn(__fadd_rn(sqi, pj.w), __fmul_rn(2.0f, dt));
  u32 bits = __float_as_uint(dd);
  return bits ^ ((u32)(((int)bits) >> 31) | 0x80000000u);
}

// ---- KNN: round-11 version verbatim (best measured: 53.9us, VGPR 52) ----
// 2048 blocks x 512 threads (8 waves). ONE wave per row, 64 candidates/lane.
// Register-lean threshold-select:
//  A: distances; hi-16 of enc packed 2/reg (denc16[32]) + EXACT lane max.
//  B: bitonic sort of 64 exact lane-max keys -> tau = 17th largest.
//  C: predicate hi16(enc) >= hi16(tau) (superset); ballot-compact; survivors
//     recompute exact enc; store exact u64 key to LDS.
//  D: bitonic sort survivors; ranks 1..16 output (rank 0 = dropped max).
// Key (enc<<32)|(4095-j) == jax top_k order (value desc, index asc).
__global__ __launch_bounds__(512) void knn_kernel(const float* __restrict__ xyz,
                                                  int* __restrict__ idxOut) {
  __shared__ float4 p[N];       // 64 KB
  __shared__ u64 surv[8][64];   // 4 KB survivor buffer, per wave
  int bidx = blockIdx.x;
  int b = bidx >> 9;            // 512 blocks per batch
  int row0 = (bidx & 511) << 3; // 8 rows per block
  const float* src = xyz + b * N * 3;
  int tid = threadIdx.x;

  for (int e = tid; e < N; e += 512) {
    float x = src[3 * e], y = src[3 * e + 1], z = src[3 * e + 2];
    float sq = __fadd_rn(__fadd_rn(__fmul_rn(x, x), __fmul_rn(y, y)), __fmul_rn(z, z));
    p[e] = make_float4(x, y, z, sq);
  }
  __syncthreads();

  int lane = tid & 63;
  int wave = tid >> 6;   // 0..7 = local row
  int i = row0 + wave;   // query point within batch

  float4 pi = p[i];
  float xi = pi.x, yi = pi.y, zi = pi.z, sqi = pi.w;

  // Phase A: distances; pack hi16; exact per-lane argmax
  u32 denc16[32];
  u32 lmax = 0u; int lt = 0;
#pragma unroll
  for (int t2 = 0; t2 < 32; ++t2) {
    int t0 = t2 * 2, t1 = t0 + 1;
    float4 pj0 = p[lane + (t0 << 6)];
    float4 pj1 = p[lane + (t1 << 6)];
    u32 e0 = encdist(xi, yi, zi, sqi, pj0);
    u32 e1 = encdist(xi, yi, zi, sqi, pj1);
    if (e0 > lmax) { lmax = e0; lt = t0; }  // strict > : smallest t on tie
    if (e1 > lmax) { lmax = e1; lt = t1; }
    denc16[t2] = (e0 >> 16) | (e1 & 0xFFFF0000u);
  }

  // Phase B: sort the 64 exact lane-max keys descending; tau = 17th largest
  u64 skey = ((u64)lmax << 32) | (u32)(4095 - (lane + (lt << 6)));
#pragma unroll
  for (int k2 = 2; k2 <= 64; k2 <<= 1) {
#pragma unroll
    for (int jj = k2 >> 1; jj > 0; jj >>= 1) {
      u64 ok = __shfl_xor(skey, jj, 64);
      bool keepMax = ((lane & jj) == 0) == ((lane & k2) == 0);
      skey = (keepMax == (ok > skey)) ? ok : skey;
    }
  }
  u64 k16 = __shfl(skey, 16, 64);
  u32 tau16 = (u32)(k16 >> 48);  // hi16 of tau

  // Phase C: ballot-compact candidates with hi16(enc) >= tau16; exact-key store
  int total = 0;
#pragma unroll
  for (int t = 0; t < 64; ++t) {
    u32 h = (t & 1) ? (denc16[t >> 1] >> 16) : (denc16[t >> 1] & 0xFFFFu);
    bool pred = (h >= tau16);
    u64 bal = __ballot(pred);
    if (bal != 0ull) {  // wave-uniform skip of empty slots
      int pos = total + (int)__builtin_amdgcn_mbcnt_hi(
                            (u32)(bal >> 32),
                            __builtin_amdgcn_mbcnt_lo((u32)bal, 0u));
      if (pred && pos < 64) {
        u32 enc = encdist(xi, yi, zi, sqi, p[lane + (t << 6)]);  // exact
        surv[wave][pos] = ((u64)enc << 32) | (u32)(4095 - (lane + (t << 6)));
      }
      total += (int)__popcll(bal);
    }
  }

  if (total <= 64) {
    // Phase D: sort survivors descending (zeros pad to the end), emit 1..16.
    u64 sk = (lane < total) ? surv[wave][lane] : 0ull;
#pragma unroll
    for (int k2 = 2; k2 <= 64; k2 <<= 1) {
#pragma unroll
      for (int jj = k2 >> 1; jj > 0; jj >>= 1) {
        u64 ok = __shfl_xor(sk, jj, 64);
        bool keepMax = ((lane & jj) == 0) == ((lane & k2) == 0);
        sk = (keepMax == (ok > sk)) ? ok : sk;
      }
    }
    if (lane >= 1 && lane < 17) {
      idxOut[((long long)(b * N + i)) * K + lane - 1] = 4095 - (int)(u32)sk;
    }
  } else {
    // Fallback (degenerate ties; never on this input): exact iterative extract
    u32 cmax = lmax; u32 ct = (u32)lt;
    u64 elim = 0ull;
    for (int r = 0; r < 17; ++r) {
      u32 wmax = dpp_max64(cmax);
      u32 s_wmax = (u32)__builtin_amdgcn_readlane((int)wmax, 63);
      u64 mask = __ballot(cmax == s_wmax);
      int s_wj;
      if (__popcll(mask) == 1) {
        int l = (int)(__ffsll((long long)mask) - 1);
        int myj = lane + ((int)ct << 6);
        s_wj = __builtin_amdgcn_readlane(myj, l);
      } else {
        u32 jv = (cmax == s_wmax) ? (u32)(lane + ((int)ct << 6)) : 0xFFFFFFFFu;
#pragma unroll
        for (int off = 1; off < 64; off <<= 1) {
          u32 oj = (u32)__shfl_xor((int)jv, off, 64);
          jv = oj < jv ? oj : jv;
        }
        s_wj = (int)__builtin_amdgcn_readfirstlane((int)jv);
      }
      if (r > 0 && lane == 0)
        idxOut[((long long)(b * N + i)) * K + (r - 1)] = s_wj;
      if (r == 16) break;
      if (lane == (s_wj & 63)) {
        elim |= 1ull << (s_wj >> 6);
        cmax = 0u; ct = 0u;
        for (int t = 0; t < 64; ++t) {
          if (elim & (1ull << t)) continue;
          u32 enc = encdist(xi, yi, zi, sqi, p[lane + (t << 6)]);
          if (enc > cmax) { cmax = enc; ct = (u32)t; }
        }
      }
    }
  }
}

// ---- Abf = bf16(leaky(P)) : XCD-pair swizzled (1024 blocks x 256) ----
__global__ __launch_bounds__(256) void cvtA_kernel(const float* __restrict__ P,
                                                   unsigned short* __restrict__ Abf) {
  int b, rgrp;
  swz_batch(blockIdx.x, &b, &rgrp);
  int tid = threadIdx.x;
  size_t off = ((size_t)b * N + rgrp * 16 + (tid >> 4)) * C + (tid & 15) * 8;
  const float4* p4 = (const float4*)(P + off);
  float4 a = p4[0], c = p4[1];
  unsigned short u0 = f2bf(leaky(a.x)), u1 = f2bf(leaky(a.y));
  unsigned short u2 = f2bf(leaky(a.z)), u3 = f2bf(leaky(a.w));
  unsigned short u4 = f2bf(leaky(c.x)), u5 = f2bf(leaky(c.y));
  unsigned short u6 = f2bf(leaky(c.z)), u7 = f2bf(leaky(c.w));
  uint4 o;
  o.x = (u32)u0 | ((u32)u1 << 16);
  o.y = (u32)u2 | ((u32)u3 << 16);
  o.z = (u32)u4 | ((u32)u5 << 16);
  o.w = (u32)u6 | ((u32)u7 << 16);
  *(uint4*)(Abf + off) = o;
}

// ---- W (f32) -> bf16, all 3 blocks at once ----
__global__ __launch_bounds__(256) void cvtW_kernel(const float* __restrict__ Wc,
                                                   const float* __restrict__ Wg,
                                                   unsigned short* __restrict__ Wbf) {
  int e = blockIdx.x * 256 + threadIdx.x;  // 0..98303
  if (e < NB * C * C) Wbf[e] = f2bf(Wc[e]);
  else Wbf[e] = f2bf(Wg[e - NB * C * C]);
}

// ---- fused per-block-iter: gather-sum (bf16) + dual MFMA matmul + epilogue
// 512 blocks x 512 threads (8 waves), XCD-pair swizzled. Block = RB=32 rows
// (halves per-iter weight re-read traffic vs 16-row blocks: 64MB not 128MB).
// Wave w = col-tile w (16 cols) x 2 row-tiles. Epilogue is LDS-staged: acc
// fragments -> f32 tile -> coalesced float4/uint4 global I/O (the fragment
// layout's native store is 4B scattered).
__global__ __launch_bounds__(512) void fused_kernel(
    const float* __restrict__ Pcur, const unsigned short* __restrict__ Abf,
    const int* __restrict__ idx,
    const unsigned short* __restrict__ Wcbf, const unsigned short* __restrict__ Wgbf,
    const float* __restrict__ bc, const float* __restrict__ bg,
    float* __restrict__ Pnxt, unsigned short* __restrict__ AbfN) {
  __shared__ int ji[RB * K];              // 2 KB
  __shared__ unsigned short Sl[RB][136];  // 8.7 KB (+8 pad)
  __shared__ float Pst[RB][128];          // 16 KB epilogue staging
  int bb, rgrp;
  swz_batch(blockIdx.x, &bb, &rgrp);      // 512 blocks: rgrp 0..127
  int row0 = bb * N + rgrp * RB;          // global row
  int tid = threadIdx.x;
  ji[tid] = idx[row0 * K + tid];          // RB*K = 512 = blockDim
  __syncthreads();

  // batch base for neighbor indices (idx entries are within-batch!)
  const unsigned short* AbfB = Abf + ((size_t)bb << 12) * C;

  // gather: thread (r,g) sums 8 cols [g*8, g*8+8) of row r over 16 neighbors
  {
    int r = tid >> 4, g = tid & 15;  // r 0..31
    float s0 = 0.f, s1 = 0.f, s2 = 0.f, s3 = 0.f, s4 = 0.f, s5 = 0.f, s6 = 0.f, s7 = 0.f;
#pragma unroll
    for (int t = 0; t < K; ++t) {
      int j = ji[(r << 4) + t];
      uint4 v = *(const uint4*)(AbfB + (size_t)j * C + g * 8);
      s0 += bflo(v.x); s1 += bfhi(v.x);
      s2 += bflo(v.y); s3 += bfhi(v.y);
      s4 += bflo(v.z); s5 += bfhi(v.z);
      s6 += bflo(v.w); s7 += bfhi(v.w);
    }
    uint4 o;
    o.x = (u32)f2bf(s0) | ((u32)f2bf(s1) << 16);
    o.y = (u32)f2bf(s2) | ((u32)f2bf(s3) << 16);
    o.z = (u32)f2bf(s4) | ((u32)f2bf(s5) << 16);
    o.w = (u32)f2bf(s6) | ((u32)f2bf(s7) << 16);
    *(uint4*)(&Sl[r][g * 8]) = o;
  }
  __syncthreads();

  // MFMA: wave = col-tile ct (16 cols); 2 row-tiles (rows 0-15, 16-31).
  // A row = lane&15, k-chunk = (lane>>4)*8 ; B col = lane&15, same k-chunk.
  int lane = tid & 63, wave = tid >> 6;  // 8 waves
  int lrow = lane & 15;
  int kgrp = (lane >> 4) * 8;
  int ct = wave;
  f32x4 acc0 = {0.f, 0.f, 0.f, 0.f};
  f32x4 acc1 = {0.f, 0.f, 0.f, 0.f};
  const unsigned short* a0p = Abf + (size_t)(row0 + lrow) * C + kgrp;
  const unsigned short* a1p = Abf + (size_t)(row0 + 16 + lrow) * C + kgrp;
  const unsigned short* wcp = Wcbf + (size_t)(ct * 16 + lrow) * C + kgrp;
  const unsigned short* wgp = Wgbf + (size_t)(ct * 16 + lrow) * C + kgrp;
#pragma unroll
  for (int ks = 0; ks < 4; ++ks) {
    short8_t bC = *(const short8_t*)(wcp + ks * 32);
    short8_t av0 = *(const short8_t*)(a0p + ks * 32);
    short8_t av1 = *(const short8_t*)(a1p + ks * 32);
    acc0 = __builtin_amdgcn_mfma_f32_16x16x32_bf16(av0, bC, acc0, 0, 0, 0);
    acc1 = __builtin_amdgcn_mfma_f32_16x16x32_bf16(av1, bC, acc1, 0, 0, 0);
  }
#pragma unroll
  for (int ks = 0; ks < 4; ++ks) {
    short8_t bG = *(const short8_t*)(wgp + ks * 32);
    short8_t sv0 = *(const short8_t*)(&Sl[lrow][kgrp + ks * 32]);
    short8_t sv1 = *(const short8_t*)(&Sl[16 + lrow][kgrp + ks * 32]);
    acc0 = __builtin_amdgcn_mfma_f32_16x16x32_bf16(sv0, bG, acc0, 0, 0, 0);
    acc1 = __builtin_amdgcn_mfma_f32_16x16x32_bf16(sv1, bG, acc1, 0, 0, 0);
  }

  // stage fragments: D row=(lane>>4)*4+q, col=lane&15 (within 16x16 tile)
  {
    int colw = ct * 16 + lrow;
    int rbase = (lane >> 4) * 4;
#pragma unroll
    for (int q = 0; q < 4; ++q) {
      Pst[rbase + q][colw] = acc0[q];
      Pst[16 + rbase + q][colw] = acc1[q];
    }
  }
  __syncthreads();

  // coalesced epilogue: thread -> (row, 8 cols); float4/uint4 global I/O
  {
    int r = tid >> 4;           // 0..31
    int c8 = (tid & 15) * 8;
    size_t goff = (size_t)(row0 + r) * C + c8;
    float4 av = *(const float4*)&Pst[r][c8];
    float4 aw = *(const float4*)&Pst[r][c8 + 4];
    float4 bcv0 = *(const float4*)&bc[c8];
    float4 bcv1 = *(const float4*)&bc[c8 + 4];
    float4 bgv0 = *(const float4*)&bg[c8];
    float4 bgv1 = *(const float4*)&bg[c8 + 4];
    float4 pv0 = *(const float4*)&Pcur[goff];
    float4 pv1 = *(const float4*)&Pcur[goff + 4];
    float4 o0, o1;
    o0.x = (av.x + (bcv0.x + 16.0f * bgv0.x)) * (1.0f / 17.0f) + pv0.x;
    o0.y = (av.y + (bcv0.y + 16.0f * bgv0.y)) * (1.0f / 17.0f) + pv0.y;
    o0.z = (av.z + (bcv0.z + 16.0f * bgv0.z)) * (1.0f / 17.0f) + pv0.z;
    o0.w = (av.w + (bcv0.w + 16.0f * bgv0.w)) * (1.0f / 17.0f) + pv0.w;
    o1.x = (aw.x + (bcv1.x + 16.0f * bgv1.x)) * (1.0f / 17.0f) + pv1.x;
    o1.y = (aw.y + (bcv1.y + 16.0f * bgv1.y)) * (1.0f / 17.0f) + pv1.y;
    o1.z = (aw.z + (bcv1.z + 16.0f * bgv1.z)) * (1.0f / 17.0f) + pv1.z;
    o1.w = (aw.w + (bcv1.w + 16.0f * bgv1.w)) * (1.0f / 17.0f) + pv1.w;
    *(float4*)&Pnxt[goff] = o0;
    *(float4*)&Pnxt[goff + 4] = o1;
    if (AbfN) {
      uint4 ob;
      ob.x = (u32)f2bf(leaky(o0.x)) | ((u32)f2bf(leaky(o0.y)) << 16);
      ob.y = (u32)f2bf(leaky(o0.z)) | ((u32)f2bf(leaky(o0.w)) << 16);
      ob.z = (u32)f2bf(leaky(o1.x)) | ((u32)f2bf(leaky(o1.y)) << 16);
      ob.w = (u32)f2bf(leaky(o1.z)) | ((u32)f2bf(leaky(o1.w)) << 16);
      *(uint4*)(AbfN + goff) = ob;
    }
  }
}

extern "C" void kernel_launch(void* const* d_in, const int* in_sizes, int n_in,
                              void* d_out, int out_size, void* d_ws, size_t ws_size,
                              hipStream_t stream) {
  const float* xyz = (const float*)d_in[0];
  const float* pts = (const float*)d_in[1];
  const float* Wc = (const float*)d_in[5];
  const float* bc = (const float*)d_in[6];
  const float* Wg = (const float*)d_in[7];
  const float* bg = (const float*)d_in[8];

  const size_t PE = (size_t)B * N * C;            // 2097152 elements
  const size_t idxB = (size_t)B * N * K * 4;      // 1 MB
  const size_t WbfB = (size_t)2 * NB * C * C * 2; // 192 KB
  char* ws = (char*)d_ws;
  float* Pa            = (float*)ws;                                  // 8 MB
  int* idx             = (int*)(ws + PE * 4);                         // 1 MB
  unsigned short* Abf0 = (unsigned short*)(ws + PE * 4 + idxB);       // 4 MB
  unsigned short* Wbf  = (unsigned short*)(ws + PE * 4 + idxB + PE * 2);
  unsigned short* Abf1 = (unsigned short*)(ws + PE * 4 + idxB + PE * 2 + WbfB);
  unsigned short* Wcbf = Wbf;
  unsigned short* Wgbf = Wbf + (size_t)NB * C * C;
  const size_t need = PE * 4 + idxB + PE * 2 + WbfB + PE * 2;  // 17.2 MB
  const bool fusedAbf = (ws_size >= need);

  hipLaunchKernelGGL(cvtW_kernel, dim3((2 * NB * C * C) / 256), dim3(256), 0, stream,
                     Wc, Wg, Wbf);
  hipLaunchKernelGGL(cvtA_kernel, dim3(1024), dim3(256), 0, stream, pts, Abf0);
  hipLaunchKernelGGL(knn_kernel, dim3(2048), dim3(512), 0, stream, xyz, idx);

  // ping-pong: pts (read-only) -> d_out -> Pa -> d_out
  const float* cur = pts;
  float* nxt = (float*)d_out;
  unsigned short* AbfCur = Abf0;
  unsigned short* AbfNxt = fusedAbf ? Abf1 : Abf0;
  for (int i = 0; i < NB; ++i) {
    if (!fusedAbf && i > 0) {
      hipLaunchKernelGGL(cvtA_kernel, dim3(1024), dim3(256), 0, stream, cur, Abf0);
      AbfCur = Abf0;
    }
    unsigned short* an = (fusedAbf && i < NB - 1) ? AbfNxt : (unsigned short*)nullptr;
    hipLaunchKernelGGL(fused_kernel, dim3((B * N) / RB), dim3(512), 0, stream,
                       cur, AbfCur, idx, Wcbf + (size_t)i * C * C, Wgbf + (size_t)i * C * C,
                       bc + (size_t)i * C, bg + (size_t)i * C, nxt, an);
    cur = nxt;
    nxt = (i == 0) ? Pa : (float*)d_out;
    if (fusedAbf) { unsigned short* ta = AbfCur; AbfCur = AbfNxt; AbfNxt = ta; }
  }
}

// Round 16
// 100.147 us; speedup vs baseline: 1.3199x; 1.0526x over previous
//
#include <hip/hip_runtime.h>
#include <math.h>

#define B  4
#define N  4096
#define C  128
#define K  16
#define NB 3
#define RB 32  // fused: rows per block

typedef unsigned int u32;
typedef unsigned long long u64;
typedef __attribute__((ext_vector_type(8))) short short8_t;
typedef __attribute__((ext_vector_type(4))) float f32x4;

__device__ __forceinline__ float leaky(float x) {
  return x >= 0.f ? x : 0.01f * x;
}
__device__ __forceinline__ unsigned short f2bf(float f) {
  u32 x = __float_as_uint(f);
  return (unsigned short)((x + 0x7FFFu + ((x >> 16) & 1u)) >> 16);  // RNE
}
__device__ __forceinline__ float bflo(u32 u) { return __uint_as_float(u << 16); }
__device__ __forceinline__ float bfhi(u32 u) { return __uint_as_float(u & 0xFFFF0000u); }
__device__ __forceinline__ u32 umaxu(u32 a, u32 b) { return a > b ? a : b; }

// XCD-pair swizzle: bidx=(q*8+x) -> batch b=x>>1, row-group rgrp=2q+(x&1).
__device__ __forceinline__ void swz_batch(int bidx, int* b, int* rgrp) {
  int q = bidx >> 3, x = bidx & 7;
  *b = x >> 1;
  *rgrp = (q << 1) | (x & 1);
}

// 64-lane max reduce, pure VALU via DPP. Result valid in lane 63.
__device__ __forceinline__ u32 dpp_max64(u32 v) {
  v = umaxu(v, (u32)__builtin_amdgcn_update_dpp(0, (int)v, 0x111, 0xf, 0xf, false));
  v = umaxu(v, (u32)__builtin_amdgcn_update_dpp(0, (int)v, 0x112, 0xf, 0xf, false));
  v = umaxu(v, (u32)__builtin_amdgcn_update_dpp(0, (int)v, 0x114, 0xf, 0xf, false));
  v = umaxu(v, (u32)__builtin_amdgcn_update_dpp(0, (int)v, 0x118, 0xf, 0xf, false));
  v = umaxu(v, (u32)__builtin_amdgcn_update_dpp(0, (int)v, 0x142, 0xa, 0xf, false));
  v = umaxu(v, (u32)__builtin_amdgcn_update_dpp(0, (int)v, 0x143, 0xc, 0xf, false));
  return v;
}

// exact monotone-encoded squared distance (reference op order, no contraction)
__device__ __forceinline__ u32 encdist(float xi, float yi, float zi, float sqi,
                                       float4 pj) {
  float dt = __fadd_rn(__fmul_rn(xi, pj.x), __fmul_rn(yi, pj.y));
  dt = __fadd_rn(dt, __fmul_rn(zi, pj.z));
  float dd = __fsub_rn(__fadd_rn(sqi, pj.w), __fmul_rn(2.0f, dt));
  u32 bits = __float_as_uint(dd);
  return bits ^ ((u32)(((int)bits) >> 31) | 0x80000000u);
}

// cheap approximate distance (fma contraction allowed), clamped to >= 0.
// Used ONLY for the tau threshold / survivor predicate (with 1-quantum slack);
// exact encdist is recomputed for all survivors.
__device__ __forceinline__ float apxdist(float xi, float yi, float zi, float sqi,
                                         float4 pj) {
  float dd = (sqi + pj.w) - 2.0f * (xi * pj.x + (yi * pj.y + zi * pj.z));
  return fmaxf(dd, 0.0f);
}

// ---- KNN (faithful: k+1 LARGEST sq-dists, drop first) ----
// 2048 blocks x 512 threads (8 waves). ONE wave per row, 64 candidates/lane
// (r11 structure; r12/13/14 alternatives all regressed). Threshold-select:
//  A: APPROX distances (fma-contracted, ~5 VALU vs 13 for the exact chain);
//     hi-16 of clamped approx packed 2/reg; float running max (no index).
//  B: bitonic sort of the 64 lane-max f32 bit-patterns -> tau = 17th largest;
//     tau16 = hi16(tau) - 1 (slack covers fma-vs-exact error, which is ~1e-5
//     vs a bf16 quantum of ~0.25 at dd~50 -> provable superset of exact top17).
//  C: predicate hi16(approx) >= tau16; ballot-compact; survivors recompute
//     EXACT enc (reference op order); store exact u64 key to LDS.
//  D: bitonic sort survivors; ranks 1..16 output (rank 0 = dropped max).
// Key (enc<<32)|(4095-j) == jax top_k order (value desc, index asc).
// Fallback if total > 64 (degenerate/tied data): exact iterative extract.
__global__ __launch_bounds__(512) void knn_kernel(const float* __restrict__ xyz,
                                                  int* __restrict__ idxOut) {
  __shared__ float4 p[N];       // 64 KB
  __shared__ u64 surv[8][64];   // 4 KB survivor buffer, per wave
  int bidx = blockIdx.x;
  int b = bidx >> 9;            // 512 blocks per batch
  int row0 = (bidx & 511) << 3; // 8 rows per block
  const float* src = xyz + b * N * 3;
  int tid = threadIdx.x;

  for (int e = tid; e < N; e += 512) {
    float x = src[3 * e], y = src[3 * e + 1], z = src[3 * e + 2];
    // sq = (x*x + y*y) + z*z, exact f32 rounding, no FMA contraction
    float sq = __fadd_rn(__fadd_rn(__fmul_rn(x, x), __fmul_rn(y, y)), __fmul_rn(z, z));
    p[e] = make_float4(x, y, z, sq);
  }
  __syncthreads();

  int lane = tid & 63;
  int wave = tid >> 6;   // 0..7 = local row
  int i = row0 + wave;   // query point within batch

  float4 pi = p[i];
  float xi = pi.x, yi = pi.y, zi = pi.z, sqi = pi.w;

  // Phase A: approx distances; pack hi16; float running max
  u32 denc16[32];
  float fmx = 0.0f;
#pragma unroll
  for (int t2 = 0; t2 < 32; ++t2) {
    int t0 = t2 * 2, t1 = t0 + 1;
    float4 pj0 = p[lane + (t0 << 6)];
    float4 pj1 = p[lane + (t1 << 6)];
    float d0 = apxdist(xi, yi, zi, sqi, pj0);
    float d1 = apxdist(xi, yi, zi, sqi, pj1);
    fmx = fmaxf(fmx, fmaxf(d0, d1));
    denc16[t2] = (__float_as_uint(d0) >> 16) | (__float_as_uint(d1) & 0xFFFF0000u);
  }

  // Phase B: sort the 64 lane-max values (u32 bits, all >= +0) descending
  u32 sv = __float_as_uint(fmx);
#pragma unroll
  for (int k2 = 2; k2 <= 64; k2 <<= 1) {
#pragma unroll
    for (int jj = k2 >> 1; jj > 0; jj >>= 1) {
      u32 ov = (u32)__shfl_xor((int)sv, jj, 64);
      bool keepMax = ((lane & jj) == 0) == ((lane & k2) == 0);
      sv = (keepMax == (ov > sv)) ? ov : sv;
    }
  }
  u32 th = ((u32)__shfl((int)sv, 16, 64)) >> 16;
  u32 tau16 = (th > 0u) ? (th - 1u) : 0u;  // 1-quantum slack (superset)

  // Phase C: ballot-compact candidates with hi16(approx) >= tau16; exact keys
  int total = 0;
#pragma unroll
  for (int t = 0; t < 64; ++t) {
    u32 h = (t & 1) ? (denc16[t >> 1] >> 16) : (denc16[t >> 1] & 0xFFFFu);
    bool pred = (h >= tau16);
    u64 bal = __ballot(pred);
    if (bal != 0ull) {  // wave-uniform skip of empty slots
      int pos = total + (int)__builtin_amdgcn_mbcnt_hi(
                            (u32)(bal >> 32),
                            __builtin_amdgcn_mbcnt_lo((u32)bal, 0u));
      if (pred && pos < 64) {
        u32 enc = encdist(xi, yi, zi, sqi, p[lane + (t << 6)]);  // exact
        surv[wave][pos] = ((u64)enc << 32) | (u32)(4095 - (lane + (t << 6)));
      }
      total += (int)__popcll(bal);
    }
  }

  if (total <= 64) {
    // Phase D: sort survivors descending (zeros pad to the end), emit 1..16.
    u64 sk = (lane < total) ? surv[wave][lane] : 0ull;
#pragma unroll
    for (int k2 = 2; k2 <= 64; k2 <<= 1) {
#pragma unroll
      for (int jj = k2 >> 1; jj > 0; jj >>= 1) {
        u64 ok = __shfl_xor(sk, jj, 64);
        bool keepMax = ((lane & jj) == 0) == ((lane & k2) == 0);
        sk = (keepMax == (ok > sk)) ? ok : sk;
      }
    }
    if (lane >= 1 && lane < 17) {
      idxOut[((long long)(b * N + i)) * K + lane - 1] = 4095 - (int)(u32)sk;
    }
  } else {
    // Fallback (degenerate ties; never on this input): exact iterative
    // extraction; recomputes its own exact argmax first.
    u32 cmax = 0u; u32 ct = 0u;
#pragma unroll
    for (int t = 0; t < 64; ++t) {
      u32 enc = encdist(xi, yi, zi, sqi, p[lane + (t << 6)]);
      if (enc > cmax) { cmax = enc; ct = (u32)t; }
    }
    u64 elim = 0ull;
    for (int r = 0; r < 17; ++r) {
      u32 wmax = dpp_max64(cmax);
      u32 s_wmax = (u32)__builtin_amdgcn_readlane((int)wmax, 63);
      u64 mask = __ballot(cmax == s_wmax);
      int s_wj;
      if (__popcll(mask) == 1) {
        int l = (int)(__ffsll((long long)mask) - 1);
        int myj = lane + ((int)ct << 6);
        s_wj = __builtin_amdgcn_readlane(myj, l);
      } else {
        u32 jv = (cmax == s_wmax) ? (u32)(lane + ((int)ct << 6)) : 0xFFFFFFFFu;
#pragma unroll
        for (int off = 1; off < 64; off <<= 1) {
          u32 oj = (u32)__shfl_xor((int)jv, off, 64);
          jv = oj < jv ? oj : jv;
        }
        s_wj = (int)__builtin_amdgcn_readfirstlane((int)jv);
      }
      if (r > 0 && lane == 0)
        idxOut[((long long)(b * N + i)) * K + (r - 1)] = s_wj;
      if (r == 16) break;
      if (lane == (s_wj & 63)) {
        elim |= 1ull << (s_wj >> 6);
        cmax = 0u; ct = 0u;
        for (int t = 0; t < 64; ++t) {
          if (elim & (1ull << t)) continue;
          u32 enc = encdist(xi, yi, zi, sqi, p[lane + (t << 6)]);
          if (enc > cmax) { cmax = enc; ct = (u32)t; }
        }
      }
    }
  }
}

// ---- Abf = bf16(leaky(P)) : XCD-pair swizzled (1024 blocks x 256) ----
__global__ __launch_bounds__(256) void cvtA_kernel(const float* __restrict__ P,
                                                   unsigned short* __restrict__ Abf) {
  int b, rgrp;
  swz_batch(blockIdx.x, &b, &rgrp);
  int tid = threadIdx.x;
  size_t off = ((size_t)b * N + rgrp * 16 + (tid >> 4)) * C + (tid & 15) * 8;
  const float4* p4 = (const float4*)(P + off);
  float4 a = p4[0], c = p4[1];
  unsigned short u0 = f2bf(leaky(a.x)), u1 = f2bf(leaky(a.y));
  unsigned short u2 = f2bf(leaky(a.z)), u3 = f2bf(leaky(a.w));
  unsigned short u4 = f2bf(leaky(c.x)), u5 = f2bf(leaky(c.y));
  unsigned short u6 = f2bf(leaky(c.z)), u7 = f2bf(leaky(c.w));
  uint4 o;
  o.x = (u32)u0 | ((u32)u1 << 16);
  o.y = (u32)u2 | ((u32)u3 << 16);
  o.z = (u32)u4 | ((u32)u5 << 16);
  o.w = (u32)u6 | ((u32)u7 << 16);
  *(uint4*)(Abf + off) = o;
}

// ---- W (f32) -> bf16, all 3 blocks at once ----
__global__ __launch_bounds__(256) void cvtW_kernel(const float* __restrict__ Wc,
                                                   const float* __restrict__ Wg,
                                                   unsigned short* __restrict__ Wbf) {
  int e = blockIdx.x * 256 + threadIdx.x;  // 0..98303
  if (e < NB * C * C) Wbf[e] = f2bf(Wc[e]);
  else Wbf[e] = f2bf(Wg[e - NB * C * C]);
}

// ---- fused per-block-iter: gather-sum (bf16) + dual MFMA matmul + epilogue
// 512 blocks x 512 threads (8 waves), XCD-pair swizzled. Block = RB=32 rows.
// Wave w = col-tile w (16 cols) x 2 row-tiles. LDS-staged coalesced epilogue.
__global__ __launch_bounds__(512) void fused_kernel(
    const float* __restrict__ Pcur, const unsigned short* __restrict__ Abf,
    const int* __restrict__ idx,
    const unsigned short* __restrict__ Wcbf, const unsigned short* __restrict__ Wgbf,
    const float* __restrict__ bc, const float* __restrict__ bg,
    float* __restrict__ Pnxt, unsigned short* __restrict__ AbfN) {
  __shared__ int ji[RB * K];              // 2 KB
  __shared__ unsigned short Sl[RB][136];  // 8.7 KB (+8 pad)
  __shared__ float Pst[RB][128];          // 16 KB epilogue staging
  int bb, rgrp;
  swz_batch(blockIdx.x, &bb, &rgrp);      // 512 blocks: rgrp 0..127
  int row0 = bb * N + rgrp * RB;          // global row
  int tid = threadIdx.x;
  ji[tid] = idx[row0 * K + tid];          // RB*K = 512 = blockDim
  __syncthreads();

  // batch base for neighbor indices (idx entries are within-batch!)
  const unsigned short* AbfB = Abf + ((size_t)bb << 12) * C;

  // gather: thread (r,g) sums 8 cols [g*8, g*8+8) of row r over 16 neighbors
  {
    int r = tid >> 4, g = tid & 15;  // r 0..31
    float s0 = 0.f, s1 = 0.f, s2 = 0.f, s3 = 0.f, s4 = 0.f, s5 = 0.f, s6 = 0.f, s7 = 0.f;
#pragma unroll
    for (int t = 0; t < K; ++t) {
      int j = ji[(r << 4) + t];
      uint4 v = *(const uint4*)(AbfB + (size_t)j * C + g * 8);
      s0 += bflo(v.x); s1 += bfhi(v.x);
      s2 += bflo(v.y); s3 += bfhi(v.y);
      s4 += bflo(v.z); s5 += bfhi(v.z);
      s6 += bflo(v.w); s7 += bfhi(v.w);
    }
    uint4 o;
    o.x = (u32)f2bf(s0) | ((u32)f2bf(s1) << 16);
    o.y = (u32)f2bf(s2) | ((u32)f2bf(s3) << 16);
    o.z = (u32)f2bf(s4) | ((u32)f2bf(s5) << 16);
    o.w = (u32)f2bf(s6) | ((u32)f2bf(s7) << 16);
    *(uint4*)(&Sl[r][g * 8]) = o;
  }
  __syncthreads();

  // MFMA: wave = col-tile ct (16 cols); 2 row-tiles (rows 0-15, 16-31).
  // A row = lane&15, k-chunk = (lane>>4)*8 ; B col = lane&15, same k-chunk.
  int lane = tid & 63, wave = tid >> 6;  // 8 waves
  int lrow = lane & 15;
  int kgrp = (lane >> 4) * 8;
  int ct = wave;
  f32x4 acc0 = {0.f, 0.f, 0.f, 0.f};
  f32x4 acc1 = {0.f, 0.f, 0.f, 0.f};
  const unsigned short* a0p = Abf + (size_t)(row0 + lrow) * C + kgrp;
  const unsigned short* a1p = Abf + (size_t)(row0 + 16 + lrow) * C + kgrp;
  const unsigned short* wcp = Wcbf + (size_t)(ct * 16 + lrow) * C + kgrp;
  const unsigned short* wgp = Wgbf + (size_t)(ct * 16 + lrow) * C + kgrp;
#pragma unroll
  for (int ks = 0; ks < 4; ++ks) {
    short8_t bC = *(const short8_t*)(wcp + ks * 32);
    short8_t av0 = *(const short8_t*)(a0p + ks * 32);
    short8_t av1 = *(const short8_t*)(a1p + ks * 32);
    acc0 = __builtin_amdgcn_mfma_f32_16x16x32_bf16(av0, bC, acc0, 0, 0, 0);
    acc1 = __builtin_amdgcn_mfma_f32_16x16x32_bf16(av1, bC, acc1, 0, 0, 0);
  }
#pragma unroll
  for (int ks = 0; ks < 4; ++ks) {
    short8_t bG = *(const short8_t*)(wgp + ks * 32);
    short8_t sv0 = *(const short8_t*)(&Sl[lrow][kgrp + ks * 32]);
    short8_t sv1 = *(const short8_t*)(&Sl[16 + lrow][kgrp + ks * 32]);
    acc0 = __builtin_amdgcn_mfma_f32_16x16x32_bf16(sv0, bG, acc0, 0, 0, 0);
    acc1 = __builtin_amdgcn_mfma_f32_16x16x32_bf16(sv1, bG, acc1, 0, 0, 0);
  }

  // stage fragments: D row=(lane>>4)*4+q, col=lane&15 (within 16x16 tile)
  {
    int colw = ct * 16 + lrow;
    int rbase = (lane >> 4) * 4;
#pragma unroll
    for (int q = 0; q < 4; ++q) {
      Pst[rbase + q][colw] = acc0[q];
      Pst[16 + rbase + q][colw] = acc1[q];
    }
  }
  __syncthreads();

  // coalesced epilogue: thread -> (row, 8 cols); float4/uint4 global I/O
  {
    int r = tid >> 4;           // 0..31
    int c8 = (tid & 15) * 8;
    size_t goff = (size_t)(row0 + r) * C + c8;
    float4 av = *(const float4*)&Pst[r][c8];
    float4 aw = *(const float4*)&Pst[r][c8 + 4];
    float4 bcv0 = *(const float4*)&bc[c8];
    float4 bcv1 = *(const float4*)&bc[c8 + 4];
    float4 bgv0 = *(const float4*)&bg[c8];
    float4 bgv1 = *(const float4*)&bg[c8 + 4];
    float4 pv0 = *(const float4*)&Pcur[goff];
    float4 pv1 = *(const float4*)&Pcur[goff + 4];
    float4 o0, o1;
    o0.x = (av.x + (bcv0.x + 16.0f * bgv0.x)) * (1.0f / 17.0f) + pv0.x;
    o0.y = (av.y + (bcv0.y + 16.0f * bgv0.y)) * (1.0f / 17.0f) + pv0.y;
    o0.z = (av.z + (bcv0.z + 16.0f * bgv0.z)) * (1.0f / 17.0f) + pv0.z;
    o0.w = (av.w + (bcv0.w + 16.0f * bgv0.w)) * (1.0f / 17.0f) + pv0.w;
    o1.x = (aw.x + (bcv1.x + 16.0f * bgv1.x)) * (1.0f / 17.0f) + pv1.x;
    o1.y = (aw.y + (bcv1.y + 16.0f * bgv1.y)) * (1.0f / 17.0f) + pv1.y;
    o1.z = (aw.z + (bcv1.z + 16.0f * bgv1.z)) * (1.0f / 17.0f) + pv1.z;
    o1.w = (aw.w + (bcv1.w + 16.0f * bgv1.w)) * (1.0f / 17.0f) + pv1.w;
    *(float4*)&Pnxt[goff] = o0;
    *(float4*)&Pnxt[goff + 4] = o1;
    if (AbfN) {
      uint4 ob;
      ob.x = (u32)f2bf(leaky(o0.x)) | ((u32)f2bf(leaky(o0.y)) << 16);
      ob.y = (u32)f2bf(leaky(o0.z)) | ((u32)f2bf(leaky(o0.w)) << 16);
      ob.z = (u32)f2bf(leaky(o1.x)) | ((u32)f2bf(leaky(o1.y)) << 16);
      ob.w = (u32)f2bf(leaky(o1.z)) | ((u32)f2bf(leaky(o1.w)) << 16);
      *(uint4*)(AbfN + goff) = ob;
    }
  }
}

extern "C" void kernel_launch(void* const* d_in, const int* in_sizes, int n_in,
                              void* d_out, int out_size, void* d_ws, size_t ws_size,
                              hipStream_t stream) {
  const float* xyz = (const float*)d_in[0];
  const float* pts = (const float*)d_in[1];
  const float* Wc = (const float*)d_in[5];
  const float* bc = (const float*)d_in[6];
  const float* Wg = (const float*)d_in[7];
  const float* bg = (const float*)d_in[8];

  const size_t PE = (size_t)B * N * C;            // 2097152 elements
  const size_t idxB = (size_t)B * N * K * 4;      // 1 MB
  const size_t WbfB = (size_t)2 * NB * C * C * 2; // 192 KB
  char* ws = (char*)d_ws;
  float* Pa            = (float*)ws;                                  // 8 MB
  int* idx             = (int*)(ws + PE * 4);                         // 1 MB
  unsigned short* Abf0 = (unsigned short*)(ws + PE * 4 + idxB);       // 4 MB
  unsigned short* Wbf  = (unsigned short*)(ws + PE * 4 + idxB + PE * 2);
  unsigned short* Abf1 = (unsigned short*)(ws + PE * 4 + idxB + PE * 2 + WbfB);
  unsigned short* Wcbf = Wbf;
  unsigned short* Wgbf = Wbf + (size_t)NB * C * C;
  const size_t need = PE * 4 + idxB + PE * 2 + WbfB + PE * 2;  // 17.2 MB
  const bool fusedAbf = (ws_size >= need);

  hipLaunchKernelGGL(cvtW_kernel, dim3((2 * NB * C * C) / 256), dim3(256), 0, stream,
                     Wc, Wg, Wbf);
  hipLaunchKernelGGL(cvtA_kernel, dim3(1024), dim3(256), 0, stream, pts, Abf0);
  hipLaunchKernelGGL(knn_kernel, dim3(2048), dim3(512), 0, stream, xyz, idx);

  // ping-pong: pts (read-only) -> d_out -> Pa -> d_out
  const float* cur = pts;
  float* nxt = (float*)d_out;
  unsigned short* AbfCur = Abf0;
  unsigned short* AbfNxt = fusedAbf ? Abf1 : Abf0;
  for (int i = 0; i < NB; ++i) {
    if (!fusedAbf && i > 0) {
      hipLaunchKernelGGL(cvtA_kernel, dim3(1024), dim3(256), 0, stream, cur, Abf0);
      AbfCur = Abf0;
    }
    unsigned short* an = (fusedAbf && i < NB - 1) ? AbfNxt : (unsigned short*)nullptr;
    hipLaunchKernelGGL(fused_kernel, dim3((B * N) / RB), dim3(512), 0, stream,
                       cur, AbfCur, idx, Wcbf + (size_t)i * C * C, Wgbf + (size_t)i * C * C,
                       bc + (size_t)i * C, bg + (size_t)i * C, nxt, an);
    cur = nxt;
    nxt = (i == 0) ? Pa : (float*)d_out;
    if (fusedAbf) { unsigned short* ta = AbfCur; AbfCur = AbfNxt; AbfNxt = ta; }
  }
}